// Round 16
// baseline (278.909 us; speedup 1.0000x reference)
//
#include <hip/hip_runtime.h>
#include <cstddef>
#include <cstdint>

#define D_MODEL 1024
#define D_STATE 16
#define D_CONV 4
#define D_INNER 2048
#define IN_DIM 256
#define OUT_DIM 256
#define BATCH 2
#define SEQ 1024
#define NTOK (BATCH*SEQ)
#define PROJ_N (2*D_STATE + D_INNER) // 2080
#define CHUNK 16
#define NCHUNK (SEQ/CHUNK)           // 64

typedef __attribute__((ext_vector_type(8))) short bf16x8;
typedef __attribute__((ext_vector_type(4))) float f32x4;

__device__ __forceinline__ float siluf(float x){ return x / (1.f + __expf(-x)); }

__device__ __forceinline__ unsigned short f2bf(float f) {
  uint32_t x = __float_as_uint(f);
  uint32_t r = x + 0x7fffu + ((x >> 16) & 1u);
  return (unsigned short)(r >> 16);
}
__device__ __forceinline__ float bf2f(unsigned short u) {
  return __uint_as_float(((uint32_t)u) << 16);
}

__device__ __forceinline__ void gload16(const void* g, void* l) {
  __builtin_amdgcn_global_load_lds((const __attribute__((address_space(1))) void*)g,
                                   (__attribute__((address_space(3))) void*)l, 16, 0, 0);
}

template<int k, typename T, int N>
__device__ __forceinline__ T (&pick4(T (&a)[N], T (&b)[N], T (&c)[N], T (&d)[N]))[N] {
  if constexpr (k == 0) return a; else if constexpr (k == 1) return b;
  else if constexpr (k == 2) return c; else return d;
}

// ------------- fused weight prep: 5 transposes + 2 casts + WxT pad zero ------
__device__ __forceinline__ void tc_tile(float (*tile)[33], const float* __restrict__ in,
                                        unsigned short* __restrict__ out,
                                        int R, int C, int tcx, int tcy, int tid)
{
  const int bc = tcx * 32, br = tcy * 32;
  const int tx = tid & 31, ty = tid >> 5;
  #pragma unroll
  for (int i = 0; i < 4; ++i) {
    int r = ty + i*8;
    tile[r][tx] = in[(size_t)(br + r)*C + bc + tx];
  }
  __syncthreads();
  const int otx = tid & 7, oty = tid >> 3;
  ushort4 v;
  v.x = f2bf(tile[otx*4+0][oty]);
  v.y = f2bf(tile[otx*4+1][oty]);
  v.z = f2bf(tile[otx*4+2][oty]);
  v.w = f2bf(tile[otx*4+3][oty]);
  *(ushort4*)&out[(size_t)(bc + oty)*R + br + otx*4] = v;
}

__global__ __launch_bounds__(256)
void prep_k(const float* __restrict__ x, const float* __restrict__ Wiw,
            const float* __restrict__ Win, const float* __restrict__ Wx,
            const float* __restrict__ Wdt, const float* __restrict__ Wout,
            const float* __restrict__ Wwr,
            unsigned short* __restrict__ xb16, unsigned short* __restrict__ WiwT,
            unsigned short* __restrict__ WinT, unsigned short* __restrict__ WxT,
            unsigned short* __restrict__ WdtT, unsigned short* __restrict__ Wob,
            unsigned short* __restrict__ WwrT)
{
  __shared__ float tile[32][33];
  const int tid = threadIdx.x;
  int id = blockIdx.x;
  if (id < 4096)  { tc_tile(tile, Win,  WinT,  1024, 4096, id % 128, id / 128, tid); return; }
  id -= 4096;
  if (id < 4160)  { tc_tile(tile, Wx,   WxT,   2048, 2080, id % 65,  id / 65,  tid); return; }
  id -= 4160;
  if (id < 4096)  { tc_tile(tile, Wdt,  WdtT,  2048, 2048, id % 64,  id / 64,  tid); return; }
  id -= 4096;
  if (id < 2048) {                                 // cast W_out -> bf16 (no transpose)
    int i = id * 256 + tid;
    float4 v = ((const float4*)Wout)[i];
    ushort4 o;
    o.x = f2bf(v.x); o.y = f2bf(v.y); o.z = f2bf(v.z); o.w = f2bf(v.w);
    ((ushort4*)Wob)[i] = o;
    return;
  }
  id -= 2048;
  if (id < 256)   { tc_tile(tile, Wwr,  WwrT,  1024, 256,  id % 8,   id / 8,   tid); return; }
  id -= 256;
  if (id < 256)   { tc_tile(tile, Wiw,  WiwT,  256,  1024, id % 32,  id / 32,  tid); return; }
  id -= 256;
  if (id < 512) {                                  // cast x -> bf16 (float4)
    int i = id * 256 + tid;
    float4 v = ((const float4*)x)[i];
    ushort4 o;
    o.x = f2bf(v.x); o.y = f2bf(v.y); o.z = f2bf(v.z); o.w = f2bf(v.w);
    ((ushort4*)xb16)[i] = o;
    return;
  }
  id -= 512;
  {                                                // zero WxT pad rows 2080..2175
    unsigned short* p = WxT + (size_t)(2080 + id) * 2048 + tid * 8;
    ushort4 z = {0,0,0,0};
    *(ushort4*)p = z; *(ushort4*)(p + 4) = z;
  }
}

// ---------- gemm2ph: 128x128 tile, BK=64, 8 waves, 2-phase schedule ----------
// DEPTH=2: stage(next) before compute, vmcnt(0)+barrier per tile (r15-proven).
// DEPTH=3: 3 LDS buffers, counted vmcnt(4) (stage t+1 verified, t+2 in flight),
//          ONE barrier per tile, never drains to 0 in main loop (T4).
// MODE: 1 softplus(v+bias) f32; 3 split xz; 4 proj split
template<int MODE, int DEPTH>
__global__ __launch_bounds__(512)
void gemm2ph(const unsigned short* __restrict__ A, const unsigned short* __restrict__ B,
             int M, int N, int K, int lda, int ldb,
             const float* __restrict__ bias,
             void* __restrict__ out0, void* __restrict__ out1)
{
  __shared__ __align__(1024) unsigned short S[DEPTH][256*64];   // 32 KB each
  const int tid = threadIdx.x;
  const int lane = tid & 63, w = tid >> 6;
  const int row0 = blockIdx.y * 128, col0 = blockIdx.x * 128;
  const int wr = (w >> 2) * 64, wc = (w & 3) * 32;
  const int l15 = lane & 15, lg4 = lane >> 4;

  int afo[4][2], bfo[2][2];
  #pragma unroll
  for (int fi = 0; fi < 4; ++fi)
    #pragma unroll
    for (int h = 0; h < 2; ++h) {
      const int r = wr + fi*16 + l15;
      const int q = h*4 + lg4;
      afo[fi][h] = r*64 + (q ^ (r & 7))*8;
    }
  #pragma unroll
  for (int fj = 0; fj < 2; ++fj)
    #pragma unroll
    for (int h = 0; h < 2; ++h) {
      const int r = wc + fj*16 + l15;
      const int q = h*4 + lg4;
      bfo[fj][h] = (128 + r)*64 + (q ^ (r & 7))*8;
    }

  const unsigned short* src[4];
  int dsto[4];
  #pragma unroll
  for (int i = 0; i < 4; ++i) {
    const int base = w*32 + i*8;
    const int row = base + (lane >> 3);
    const int gs = (lane & 7) ^ (row & 7);
    dsto[i] = base*64;
    src[i] = (row < 128) ? A + (size_t)(row0 + row) * lda + gs*8
                         : B + (size_t)(col0 + row - 128) * ldb + gs*8;
  }

  f32x4 acc[4][2];
  #pragma unroll
  for (int i=0;i<4;i++)
    #pragma unroll
    for (int j=0;j<2;j++) acc[i][j] = (f32x4){0.f,0.f,0.f,0.f};

  const int NT = K >> 6;

  auto stage = [&](int buf) {
    #pragma unroll
    for (int i = 0; i < 4; ++i) { gload16(src[i], &S[buf][dsto[i]]); src[i] += 64; }
  };
  auto compute = [&](const unsigned short* Sb) {
    #pragma unroll
    for (int h = 0; h < 2; ++h) {
      bf16x8 af[4], bfv[2];
      #pragma unroll
      for (int fi = 0; fi < 4; ++fi) af[fi] = *(const bf16x8*)(Sb + afo[fi][h]);
      #pragma unroll
      for (int fj = 0; fj < 2; ++fj) bfv[fj] = *(const bf16x8*)(Sb + bfo[fj][h]);
      __builtin_amdgcn_s_setprio(1);
      #pragma unroll
      for (int fi = 0; fi < 4; ++fi)
        #pragma unroll
        for (int fj = 0; fj < 2; ++fj)
          acc[fi][fj] = __builtin_amdgcn_mfma_f32_16x16x32_bf16(af[fi], bfv[fj], acc[fi][fj], 0, 0, 0);
      __builtin_amdgcn_s_setprio(0);
    }
  };

  if constexpr (DEPTH == 2) {
    stage(0);
    asm volatile("s_waitcnt vmcnt(0)" ::: "memory");
    __builtin_amdgcn_s_barrier();
    asm volatile("" ::: "memory");
    int cur = 0;
    for (int t = 0; t < NT; ++t) {
      if (t + 1 < NT) stage(cur ^ 1);
      compute(&S[cur][0]);
      asm volatile("s_waitcnt vmcnt(0) lgkmcnt(0)" ::: "memory");
      __builtin_amdgcn_s_barrier();
      asm volatile("" ::: "memory");
      cur ^= 1;
    }
  } else {
    stage(0);
    if (NT > 1) stage(1);
    int cur = 0;
    for (int t = 0; t < NT; ++t) {
      if (t + 1 < NT) asm volatile("s_waitcnt vmcnt(4)" ::: "memory");
      else            asm volatile("s_waitcnt vmcnt(0)" ::: "memory");
      __builtin_amdgcn_s_barrier();
      asm volatile("" ::: "memory");
      if (t + 2 < NT) stage((cur + 2) % 3);
      compute(&S[cur][0]);
      cur = (cur + 1) % 3;
    }
  }

  #pragma unroll
  for (int fi=0; fi<4; fi++){
    const int rb = row0 + wr + fi*16 + lg4*4;
    #pragma unroll
    for (int fj=0; fj<2; fj++){
      const int c = col0 + wc + fj*16 + l15;
      #pragma unroll
      for (int q=0;q<4;q++){
        const int r = rb + q;
        float v = acc[fi][fj][q];
        if constexpr (MODE == 1) {
          if (c < N) { v += bias[c]; v = (v > 20.f) ? v : log1pf(__expf(v));
                       ((float*)out0)[(size_t)r*N + c] = v; }
        } else if constexpr (MODE == 3) {
          if (c < 2048) ((float*)out0)[(size_t)r*2048 + c] = v;
          else          ((unsigned short*)out1)[(size_t)r*2048 + (c - 2048)] = f2bf(v);
        } else {
          if (c < 32) ((float*)out0)[(size_t)r*32 + c] = v;
          else if (c < N) ((unsigned short*)out1)[(size_t)r*2048 + (c - 32)] = f2bf(v);
        }
      }
    }
  }
}

// ------------- bf16 MFMA GEMM, reg-staged, depth-4 register pipeline ---------
// MODE: 0 f32 out (+bias); 2 bf16 out; 5 split-K fp32 partials.
template<int BM, int BN, int MODE>
__global__ __launch_bounds__(256)
void gemm_bf16(const unsigned short* __restrict__ A, const unsigned short* __restrict__ B,
               int M, int N, int K, int lda, int ldb,
               const float* __restrict__ bias,
               void* __restrict__ out0, void* __restrict__ out1)
{
  constexpr int FM = BM / 32;
  constexpr int FN = BN / 32;
  constexpr int ROWS = BM + BN;
  constexpr int GR = ROWS / 64;
  __shared__ __align__(1024) unsigned short S[2][ROWS*32];

  const int tid = threadIdx.x;
  const int lane = tid & 63, w = tid >> 6;
  const int row0 = blockIdx.y * BM, col0 = blockIdx.x * BN;
  const int wr = (w >> 1) * (BM/2), wc = (w & 1) * (BN/2);
  const int l15 = lane & 15, lg4 = lane >> 4;

  size_t zoff = 0;
  if constexpr (MODE == 5) {
    A += (size_t)blockIdx.z * (size_t)K;
    B += (size_t)blockIdx.z * (size_t)K;
    zoff = (size_t)blockIdx.z * (size_t)(gridDim.y * BM) * (size_t)N;
  }

  int afo[FM], bfo[FN];
  #pragma unroll
  for (int fi = 0; fi < FM; ++fi) {
    const int r = wr + fi*16 + l15;
    afo[fi] = r*32 + (lg4 ^ ((r >> 1) & 3))*8;
  }
  #pragma unroll
  for (int fj = 0; fj < FN; ++fj) {
    const int r = wc + fj*16 + l15;
    bfo[fj] = (BM + r)*32 + (lg4 ^ ((r >> 1) & 3))*8;
  }

  const unsigned short* src[GR];
  int ldso[GR];
  #pragma unroll
  for (int i = 0; i < GR; ++i) {
    const int g = tid + i*256;
    const int row = g >> 2, q = g & 3;
    ldso[i] = row*32 + (q ^ ((row >> 1) & 3))*8;
    src[i] = (row < BM) ? A + (size_t)(row0 + row) * lda + q*8
                        : B + (size_t)(col0 + row - BM) * ldb + q*8;
  }

  f32x4 acc[FM][FN];
  #pragma unroll
  for (int i=0;i<FM;i++)
    #pragma unroll
    for (int j=0;j<FN;j++) acc[i][j] = (f32x4){0.f,0.f,0.f,0.f};

  const int NT = K >> 5;
  bf16x8 g0[GR], g1[GR], g2[GR], g3[GR];

  auto loadg = [&](bf16x8 (&g)[GR]) {
    #pragma unroll
    for (int i = 0; i < GR; ++i) { g[i] = *(const bf16x8*)src[i]; src[i] += 32; }
  };

  loadg(g0); loadg(g1); loadg(g2); loadg(g3);
  #pragma unroll
  for (int i = 0; i < GR; ++i) *(bf16x8*)(&S[0][ldso[i]]) = g0[i];
  asm volatile("s_waitcnt lgkmcnt(0)" ::: "memory");
  __builtin_amdgcn_s_barrier();
  asm volatile("" ::: "memory");

#define STEP(I) do {                                                          \
    const int j = base + (I);                                                 \
    if (j < NT) {                                                             \
      bf16x8 af[FM], bfv[FN];                                                 \
      _Pragma("unroll")                                                       \
      for (int fi = 0; fi < FM; ++fi)                                         \
        af[fi] = *(const bf16x8*)&S[(I)&1][afo[fi]];                          \
      _Pragma("unroll")                                                       \
      for (int fj = 0; fj < FN; ++fj)                                         \
        bfv[fj] = *(const bf16x8*)&S[(I)&1][bfo[fj]];                         \
      if (j + 4 < NT) loadg(pick4<(I)&3>(g0, g1, g2, g3));                    \
      _Pragma("unroll")                                                       \
      for (int fi = 0; fi < FM; ++fi)                                         \
        _Pragma("unroll")                                                     \
        for (int fj = 0; fj < FN; ++fj)                                       \
          acc[fi][fj] = __builtin_amdgcn_mfma_f32_16x16x32_bf16(              \
              af[fi], bfv[fj], acc[fi][fj], 0, 0, 0);                         \
      if (j + 1 < NT) {                                                       \
        bf16x8 (&gw)[GR] = pick4<((I)+1)&3>(g0, g1, g2, g3);                  \
        _Pragma("unroll")                                                     \
        for (int i = 0; i < GR; ++i)                                          \
          *(bf16x8*)(&S[((I)+1)&1][ldso[i]]) = gw[i];                         \
      }                                                                       \
      asm volatile("s_waitcnt lgkmcnt(0)" ::: "memory");                      \
      __builtin_amdgcn_s_barrier();                                           \
      asm volatile("" ::: "memory");                                          \
    }                                                                         \
  } while (0)

  for (int base = 0; base < NT; base += 4) {
    STEP(0); STEP(1); STEP(2); STEP(3);
  }
#undef STEP

  #pragma unroll
  for (int fi=0; fi<FM; fi++){
    const int rb = row0 + wr + fi*16 + lg4*4;
    #pragma unroll
    for (int fj=0; fj<FN; fj++){
      const int c = col0 + wc + fj*16 + l15;
      #pragma unroll
      for (int q=0;q<4;q++){
        const int r = rb + q;
        float v = acc[fi][fj][q];
        if constexpr (MODE == 0) {
          if (c < N) ((float*)out0)[(size_t)r*N + c] = bias ? v + bias[c] : v;
        } else if constexpr (MODE == 2) {
          if (c < N) ((unsigned short*)out0)[(size_t)r*N + c] = f2bf(v);
        } else {
          if (c < N) ((float*)out0)[zoff + (size_t)r*N + c] = v;
        }
      }
    }
  }
}

// reduce 4 fp32 partials [256*2048] -> bf16
__global__ __launch_bounds__(256)
void red4_wf(const float* __restrict__ p, unsigned short* __restrict__ out)
{
  const size_t S = (size_t)256*2048;
  const int i = (blockIdx.x * 256 + threadIdx.x) * 4;
  float4 a = *(const float4*)(p + i);
  float4 b = *(const float4*)(p + S + i);
  float4 c = *(const float4*)(p + 2*S + i);
  float4 d = *(const float4*)(p + 3*S + i);
  ushort4 o;
  o.x = f2bf(a.x+b.x+c.x+d.x);
  o.y = f2bf(a.y+b.y+c.y+d.y);
  o.z = f2bf(a.z+b.z+c.z+d.z);
  o.w = f2bf(a.w+b.w+c.w+d.w);
  *(ushort4*)(out + i) = o;
}

// reduce 4 fp32 partials [2048*256] + bias[col] -> fp32 out
__global__ __launch_bounds__(256)
void red4_out(const float* __restrict__ p, const float* __restrict__ bias,
              float* __restrict__ out)
{
  const size_t S = (size_t)2048*256;
  const int i = (blockIdx.x * 256 + threadIdx.x) * 4;
  float4 a = *(const float4*)(p + i);
  float4 b = *(const float4*)(p + S + i);
  float4 c = *(const float4*)(p + 2*S + i);
  float4 d = *(const float4*)(p + 3*S + i);
  float4 bb = *(const float4*)(bias + (i & 255));
  float4 o;
  o.x = a.x+b.x+c.x+d.x + bb.x;
  o.y = a.y+b.y+c.y+d.y + bb.y;
  o.z = a.z+b.z+c.z+d.z + bb.z;
  o.w = a.w+b.w+c.w+d.w + bb.w;
  *(float4*)(out + i) = o;
}

// LayerNorm: read fp32 h, write bf16
__global__ __launch_bounds__(256)
void ln_k(const float* __restrict__ h, const float* __restrict__ gamma,
          const float* __restrict__ beta, unsigned short* __restrict__ hb)
{
  const int row = blockIdx.x;
  const float* p = h + (size_t)row * D_MODEL;
  float s = 0.f, s2 = 0.f;
  for (int i = threadIdx.x; i < D_MODEL; i += 256) { float v = p[i]; s += v; s2 += v*v; }
  #pragma unroll
  for (int off = 32; off; off >>= 1) { s += __shfl_down(s, off, 64); s2 += __shfl_down(s2, off, 64); }
  __shared__ float ss[4], ss2[4];
  __shared__ float smu, sinv;
  const int wid = threadIdx.x >> 6;
  if ((threadIdx.x & 63) == 0) { ss[wid] = s; ss2[wid] = s2; }
  __syncthreads();
  if (threadIdx.x == 0) {
    float S = ss[0]+ss[1]+ss[2]+ss[3];
    float S2 = ss2[0]+ss2[1]+ss2[2]+ss2[3];
    float mu = S * (1.f / D_MODEL);
    float var = S2 * (1.f / D_MODEL) - mu * mu;
    smu = mu; sinv = rsqrtf(var + 1e-5f);
  }
  __syncthreads();
  const float mu = smu, inv = sinv;
  unsigned short* q = hb + (size_t)row * D_MODEL;
  for (int i = threadIdx.x; i < D_MODEL; i += 256)
    q[i] = f2bf((p[i] - mu) * inv * gamma[i] + beta[i]);
}

// conv+silu, float4 over d: read xb fp32 [NTOK][2048], write u bf16
__global__ __launch_bounds__(256)
void conv_silu_k(const float* __restrict__ xb, const float* __restrict__ cw,
                 const float* __restrict__ cb, unsigned short* __restrict__ ub)
{
  const int idx = blockIdx.x * 256 + threadIdx.x;   // group of 4 d's
  const int d4 = (idx & 511) * 4;
  const int bt = idx >> 9;
  const int t  = bt & (SEQ - 1);
  float4 acc = *(const float4*)(cb + d4);
  const float* base = xb + (size_t)bt * D_INNER + d4;
  #pragma unroll
  for (int k = 0; k < D_CONV; ++k) {
    int tt = t + k - (D_CONV - 1);
    if (tt >= 0) {
      float4 xv = *(const float4*)(base + (ptrdiff_t)(k - (D_CONV-1)) * D_INNER);
      acc.x = fmaf(cw[(d4+0)*D_CONV + k], xv.x, acc.x);
      acc.y = fmaf(cw[(d4+1)*D_CONV + k], xv.y, acc.y);
      acc.z = fmaf(cw[(d4+2)*D_CONV + k], xv.z, acc.z);
      acc.w = fmaf(cw[(d4+3)*D_CONV + k], xv.w, acc.w);
    }
  }
  ushort4 o;
  o.x = f2bf(siluf(acc.x)); o.y = f2bf(siluf(acc.y));
  o.z = f2bf(siluf(acc.z)); o.w = f2bf(siluf(acc.w));
  *(ushort4*)(ub + (size_t)bt * D_INNER + d4) = o;
}

// ---- chunk-parallel scan, CHUNK=16, compact 17-slot summaries ----
// summ layout: [b][c][17][D_INNER]; slot 0 = dtsum, slots 1..16 = hl (p1)
// -> p2 overwrites slots 1..16 with chunk-START state; p3 reads them.
__global__ __launch_bounds__(256)
void scan_p1(const float* __restrict__ dtb, const unsigned short* __restrict__ ub,
             const float* __restrict__ BC, const float* __restrict__ A_log,
             float* __restrict__ summ)
{
  const int bid = blockIdx.x;                 // b*512 + c*8 + blk
  const int b = bid >> 9;
  const int c = (bid >> 3) & (NCHUNK - 1);
  const int d = ((bid & 7) << 8) + threadIdx.x;
  float A[D_STATE], hl[D_STATE];
  #pragma unroll
  for (int n = 0; n < D_STATE; ++n) { A[n] = -__expf(A_log[d*D_STATE + n]); hl[n] = 0.f; }
  float dtsum = 0.f;
  const size_t row0 = (size_t)b * SEQ + (size_t)c * CHUNK;
  float dtv = dtb[row0*D_INNER + d];
  float uv  = bf2f(ub[row0*D_INNER + d]);
  float Bv[D_STATE];
  #pragma unroll
  for (int n = 0; n < D_STATE; ++n) Bv[n] = BC[row0*32 + n];
  for (int t = 0; t < CHUNK; ++t) {
    const size_t rn = row0 + ((t+1 < CHUNK) ? (t+1) : t);
    float ndt = dtb[rn*D_INNER + d];
    float nu  = bf2f(ub[rn*D_INNER + d]);
    float nB[D_STATE];
    #pragma unroll
    for (int n = 0; n < D_STATE; ++n) nB[n] = BC[rn*32 + n];
    const float du = dtv * uv;
    dtsum += dtv;
    #pragma unroll
    for (int n = 0; n < D_STATE; ++n) {
      float dA = __expf(dtv * A[n]);
      hl[n] = fmaf(dA, hl[n], du * Bv[n]);
    }
    dtv = ndt; uv = nu;
    #pragma unroll
    for (int n = 0; n < D_STATE; ++n) Bv[n] = nB[n];
  }
  float* s = summ + (((size_t)b*NCHUNK + c)*17)*D_INNER + d;
  s[0] = dtsum;
  #pragma unroll
  for (int n = 0; n < D_STATE; ++n)
    s[(size_t)(1+n)*D_INNER] = hl[n];
}

__global__ __launch_bounds__(256)
void scan_p2(float* __restrict__ summ, const float* __restrict__ h0,
             const float* __restrict__ A_log, float* __restrict__ outH)
{
  const int b = blockIdx.x >> 3;
  const int d = ((blockIdx.x & 7) << 8) + threadIdx.x;
  float A[D_STATE], h[D_STATE];
  #pragma unroll
  for (int n = 0; n < D_STATE; ++n) {
    A[n] = -__expf(A_log[d*D_STATE + n]);
    h[n] = h0[((size_t)b*D_INNER + d)*D_STATE + n];
  }
  float dts, lv[D_STATE];
  float* s0 = summ + (((size_t)b*NCHUNK + 0)*17)*D_INNER + d;
  dts = s0[0];
  #pragma unroll
  for (int n = 0; n < D_STATE; ++n) lv[n] = s0[(size_t)(1+n)*D_INNER];
  for (int c = 0; c < NCHUNK; ++c) {
    float* s = summ + (((size_t)b*NCHUNK + c)*17)*D_INNER + d;
    const int cn = (c+1 < NCHUNK) ? (c+1) : c;
    float* sn = summ + (((size_t)b*NCHUNK + cn)*17)*D_INNER + d;
    float ndts = sn[0];
    float nl[D_STATE];
    #pragma unroll
    for (int n = 0; n < D_STATE; ++n) nl[n] = sn[(size_t)(1+n)*D_INNER];
    #pragma unroll
    for (int n = 0; n < D_STATE; ++n) {
      float p = __expf(A[n] * dts);            // prodDA recomputed from dtsum
      s[(size_t)(1+n)*D_INNER] = h[n];         // start state for chunk c
      h[n] = fmaf(p, h[n], lv[n]);
      lv[n] = nl[n];
    }
    dts = ndts;
  }
  #pragma unroll
  for (int n = 0; n < D_STATE; ++n)
    outH[((size_t)b*D_INNER + d)*D_STATE + n] = h[n];
}

__global__ __launch_bounds__(256)
void scan_p3(const float* __restrict__ dtb, const unsigned short* __restrict__ ub,
             const unsigned short* __restrict__ zbh, const float* __restrict__ BC,
             const float* __restrict__ A_log, const float* __restrict__ D_skip,
             const float* __restrict__ summ, unsigned short* __restrict__ yb)
{
  const int bid = blockIdx.x;
  const int b = bid >> 9;
  const int c = (bid >> 3) & (NCHUNK - 1);
  const int d = ((bid & 7) << 8) + threadIdx.x;
  float A[D_STATE], h[D_STATE];
  const float* s = summ + (((size_t)b*NCHUNK + c)*17)*D_INNER + d;
  #pragma unroll
  for (int n = 0; n < D_STATE; ++n) {
    A[n] = -__expf(A_log[d*D_STATE + n]);
    h[n] = s[(size_t)(1+n)*D_INNER];
  }
  const float Ds = D_skip[d];
  const size_t row0 = (size_t)b * SEQ + (size_t)c * CHUNK;
  float dtv = dtb[row0*D_INNER + d];
  float uv  = bf2f(ub[row0*D_INNER + d]);
  float zv  = bf2f(zbh[row0*D_INNER + d]);
  float Bv[D_STATE], Cv[D_STATE];
  #pragma unroll
  for (int n = 0; n < D_STATE; ++n) { Bv[n] = BC[row0*32 + n]; Cv[n] = BC[row0*32 + 16 + n]; }
  for (int t = 0; t < CHUNK; ++t) {
    const size_t r = row0 + t;
    const size_t rn = row0 + ((t+1 < CHUNK) ? (t+1) : t);
    float ndt = dtb[rn*D_INNER + d];
    float nu  = bf2f(ub[rn*D_INNER + d]);
    float nz  = bf2f(zbh[rn*D_INNER + d]);
    float nB[D_STATE], nC[D_STATE];
    #pragma unroll
    for (int n = 0; n < D_STATE; ++n) { nB[n] = BC[rn*32 + n]; nC[n] = BC[rn*32 + 16 + n]; }
    const float du = dtv * uv;
    float y = 0.f;
    #pragma unroll
    for (int n = 0; n < D_STATE; ++n) {
      float dA = __expf(dtv * A[n]);
      h[n] = fmaf(dA, h[n], du * Bv[n]);
      y = fmaf(h[n], Cv[n], y);
    }
    y = fmaf(uv, Ds, y);
    yb[r*D_INNER + d] = f2bf(y * siluf(zv));
    dtv = ndt; uv = nu; zv = nz;
    #pragma unroll
    for (int n = 0; n < D_STATE; ++n) { Bv[n] = nB[n]; Cv[n] = nC[n]; }
  }
}

extern "C" void kernel_launch(void* const* d_in, const int* in_sizes, int n_in,
                              void* d_out, int out_size, void* d_ws, size_t ws_size,
                              hipStream_t stream) {
  const float* x          = (const float*)d_in[0];
  const float* h0         = (const float*)d_in[1];
  const float* W_in_wrap  = (const float*)d_in[2];
  const float* b_in_wrap  = (const float*)d_in[3];
  const float* ln_g       = (const float*)d_in[4];
  const float* ln_b       = (const float*)d_in[5];
  const float* W_in       = (const float*)d_in[6];
  const float* conv_w     = (const float*)d_in[7];
  const float* conv_b     = (const float*)d_in[8];
  const float* W_x        = (const float*)d_in[9];
  const float* W_dt       = (const float*)d_in[10];
  const float* b_dt       = (const float*)d_in[11];
  const float* A_log      = (const float*)d_in[12];
  const float* D_skip     = (const float*)d_in[13];
  const float* W_out      = (const float*)d_in[14];
  const float* W_out_wrap = (const float*)d_in[15];
  const float* b_out_wrap = (const float*)d_in[16];

  float* out  = (float*)d_out;                       // (B,T,OUT_DIM)
  float* outH = out + (size_t)NTOK * OUT_DIM;        // (B,D_INNER,D_STATE)

  char* ws = (char*)d_ws;
  auto at = [&](size_t kb){ return (void*)(ws + kb*1024); };
  float*          hbuf = (float*)at(0);        // 8 MB: Wf partials -> h fp32
  float*          wfp  = hbuf;
  float*          xb   = (float*)at(8192);     // 16 MB fp32 x_branch (then dtb, then out partials)
  float*          dtb  = xb;
  float*          outp = xb;
  unsigned short* zbh  = (unsigned short*)at(24576);  // 8 MB bf16 z
  unsigned short* WfT  = (unsigned short*)at(32768);  // 1 MB bf16 W_fused^T [256][2048]
  unsigned short* ub   = (unsigned short*)at(40960);  // 8 MB bf16 u (xb16 early)
  unsigned short* xb16 = ub;
  unsigned short* gb   = (unsigned short*)at(49152);  // 8 MB bf16 gate (WiwT early; yb later)
  unsigned short* WiwT = gb;
  unsigned short* yb   = gb;
  unsigned short* hb   = (unsigned short*)at(57344);  // 4 MB bf16 h_ln
  float*          BC   = (float*)at(61440);    // 256 KB fp32 [NTOK][32]
  unsigned short* WinT = (unsigned short*)at(61696);  // 8 MB (dead after xz)
  unsigned short* WxT  = (unsigned short*)at(69888);  // 8.5 MB (dead after proj)
  float*          summ = (float*)at(61696);    // 17 MB compact summaries (over dead WinT/WxT/+0.5MB of WdtT)
  unsigned short* WdtT = (unsigned short*)at(78592);  // 8 MB (dead after dt GEMM)
  unsigned short* Wob  = (unsigned short*)at(86784);  // 4 MB W_out bf16 [2048][1024]
  unsigned short* WwrT = (unsigned short*)at(90880);  // 512 KB [256][1024] (ends 89.25 MB)

  dim3 blk(256);
  dim3 blk512(512);
  // 0) fused prep (1 launch)
  prep_k<<<dim3(15520), blk, 0, stream>>>(x, W_in_wrap, W_in, W_x, W_dt, W_out, W_out_wrap,
                                          xb16, WiwT, WinT, WxT, WdtT, Wob, WwrT);
  // 0b) Wf partials = WwrT @ Wob, split-K x4 (512 blocks, NT=8)
  gemm_bf16<64,64,5><<<dim3(2048/64, 256/64, 4), blk, 0, stream>>>(WwrT, Wob, 256, 2048, 1024/4,
                                                                   1024, 1024, nullptr, wfp, nullptr);
  // 0c) WfT = sum partials -> bf16
  red4_wf<<<dim3(512), blk, 0, stream>>>(wfp, WfT);
  // 1) h = x @ W_in_wrap + b_in_wrap  (512 blocks, NT=8)
  gemm_bf16<64,64,0><<<dim3(1024/64, NTOK/64), blk, 0, stream>>>(xb16, WiwT, NTOK, 1024, 256,
                                                                 256, 256, b_in_wrap, hbuf, nullptr);
  // 2) LayerNorm -> bf16
  ln_k<<<dim3(NTOK), blk, 0, stream>>>(hbuf, ln_g, ln_b, hb);
  // 3) xz = h @ W_in -> xb fp32 | z bf16   (2-phase depth-2, 512 blocks)
  gemm2ph<3,2><<<dim3(4096/128, NTOK/128), blk512, 0, stream>>>(hb, WinT, NTOK, 4096, 1024,
                                                                1024, 1024, nullptr, xb, zbh);
  // 4) u = silu(conv(xb)) -> bf16 (float4, 4096 blocks)
  conv_silu_k<<<dim3(NTOK*D_INNER/4/256), blk, 0, stream>>>(xb, conv_w, conv_b, ub);
  // 5) proj = u @ W_x -> BC fp32 | g bf16  (2-phase depth-3 counted vmcnt, 272 blocks)
  gemm2ph<4,3><<<dim3(2176/128, NTOK/128), blk512, 0, stream>>>(ub, WxT, NTOK, PROJ_N, 2048,
                                                                2048, 2048, nullptr, BC, gb);
  // 6) dt = softplus(g @ W_dt + b_dt) -> fp32 (2-phase depth-3, 256 blocks)
  gemm2ph<1,3><<<dim3(2048/128, NTOK/128), blk512, 0, stream>>>(gb, WdtT, NTOK, 2048, 2048,
                                                                2048, 2048, b_dt, dtb, nullptr);
  // 7) chunk-parallel scan (CHUNK=16: 1024 blocks p1/p3, 4 waves/SIMD)
  scan_p1<<<dim3(BATCH*NCHUNK*(D_INNER/256)), blk, 0, stream>>>(dtb, ub, BC, A_log, summ);
  scan_p2<<<dim3(BATCH*(D_INNER/256)), blk, 0, stream>>>(summ, h0, A_log, outH);
  scan_p3<<<dim3(BATCH*NCHUNK*(D_INNER/256)), blk, 0, stream>>>(dtb, ub, zbh, BC, A_log, D_skip, summ, yb);
  // 8) out partials = y @ W_fused, split-K x4 (512 blocks, NT=16)
  gemm_bf16<64,64,5><<<dim3(256/64, NTOK/64, 4), blk, 0, stream>>>(yb, WfT, NTOK, 256, 2048/4,
                                                                   2048, 2048, nullptr, outp, nullptr);
  // 8b) out = sum partials + b_out_wrap (fp32)
  red4_out<<<dim3(512), blk, 0, stream>>>(outp, b_out_wrap, out);
}

// Round 17
// 241.863 us; speedup vs baseline: 1.1532x; 1.1532x over previous
//
#include <hip/hip_runtime.h>
#include <cstddef>
#include <cstdint>

#define D_MODEL 1024
#define D_STATE 16
#define D_CONV 4
#define D_INNER 2048
#define IN_DIM 256
#define OUT_DIM 256
#define BATCH 2
#define SEQ 1024
#define NTOK (BATCH*SEQ)
#define PROJ_N (2*D_STATE + D_INNER) // 2080
#define CHUNK 16
#define NCHUNK (SEQ/CHUNK)           // 64
#define GROUPS 8
#define GCH (NCHUNK/GROUPS)          // 8 chunks per group

typedef __attribute__((ext_vector_type(8))) short bf16x8;
typedef __attribute__((ext_vector_type(4))) float f32x4;

__device__ __forceinline__ float siluf(float x){ return x / (1.f + __expf(-x)); }

__device__ __forceinline__ unsigned short f2bf(float f) {
  uint32_t x = __float_as_uint(f);
  uint32_t r = x + 0x7fffu + ((x >> 16) & 1u);
  return (unsigned short)(r >> 16);
}
__device__ __forceinline__ float bf2f(unsigned short u) {
  return __uint_as_float(((uint32_t)u) << 16);
}

__device__ __forceinline__ void gload16(const void* g, void* l) {
  __builtin_amdgcn_global_load_lds((const __attribute__((address_space(1))) void*)g,
                                   (__attribute__((address_space(3))) void*)l, 16, 0, 0);
}

template<int k, typename T, int N>
__device__ __forceinline__ T (&pick4(T (&a)[N], T (&b)[N], T (&c)[N], T (&d)[N]))[N] {
  if constexpr (k == 0) return a; else if constexpr (k == 1) return b;
  else if constexpr (k == 2) return c; else return d;
}

// ------------- fused weight prep: 5 transposes + 2 casts + WxT pad zero ------
__device__ __forceinline__ void tc_tile(float (*tile)[33], const float* __restrict__ in,
                                        unsigned short* __restrict__ out,
                                        int R, int C, int tcx, int tcy, int tid)
{
  const int bc = tcx * 32, br = tcy * 32;
  const int tx = tid & 31, ty = tid >> 5;
  #pragma unroll
  for (int i = 0; i < 4; ++i) {
    int r = ty + i*8;
    tile[r][tx] = in[(size_t)(br + r)*C + bc + tx];
  }
  __syncthreads();
  const int otx = tid & 7, oty = tid >> 3;
  ushort4 v;
  v.x = f2bf(tile[otx*4+0][oty]);
  v.y = f2bf(tile[otx*4+1][oty]);
  v.z = f2bf(tile[otx*4+2][oty]);
  v.w = f2bf(tile[otx*4+3][oty]);
  *(ushort4*)&out[(size_t)(bc + oty)*R + br + otx*4] = v;
}

__global__ __launch_bounds__(256)
void prep_k(const float* __restrict__ x, const float* __restrict__ Wiw,
            const float* __restrict__ Win, const float* __restrict__ Wx,
            const float* __restrict__ Wdt, const float* __restrict__ Wout,
            const float* __restrict__ Wwr,
            unsigned short* __restrict__ xb16, unsigned short* __restrict__ WiwT,
            unsigned short* __restrict__ WinT, unsigned short* __restrict__ WxT,
            unsigned short* __restrict__ WdtT, unsigned short* __restrict__ Wob,
            unsigned short* __restrict__ WwrT)
{
  __shared__ float tile[32][33];
  const int tid = threadIdx.x;
  int id = blockIdx.x;
  if (id < 4096)  { tc_tile(tile, Win,  WinT,  1024, 4096, id % 128, id / 128, tid); return; }
  id -= 4096;
  if (id < 4160)  { tc_tile(tile, Wx,   WxT,   2048, 2080, id % 65,  id / 65,  tid); return; }
  id -= 4160;
  if (id < 4096)  { tc_tile(tile, Wdt,  WdtT,  2048, 2048, id % 64,  id / 64,  tid); return; }
  id -= 4096;
  if (id < 2048) {                                 // cast W_out -> bf16 (no transpose)
    int i = id * 256 + tid;
    float4 v = ((const float4*)Wout)[i];
    ushort4 o;
    o.x = f2bf(v.x); o.y = f2bf(v.y); o.z = f2bf(v.z); o.w = f2bf(v.w);
    ((ushort4*)Wob)[i] = o;
    return;
  }
  id -= 2048;
  if (id < 256)   { tc_tile(tile, Wwr,  WwrT,  1024, 256,  id % 8,   id / 8,   tid); return; }
  id -= 256;
  if (id < 256)   { tc_tile(tile, Wiw,  WiwT,  256,  1024, id % 32,  id / 32,  tid); return; }
  id -= 256;
  if (id < 512) {                                  // cast x -> bf16 (float4)
    int i = id * 256 + tid;
    float4 v = ((const float4*)x)[i];
    ushort4 o;
    o.x = f2bf(v.x); o.y = f2bf(v.y); o.z = f2bf(v.z); o.w = f2bf(v.w);
    ((ushort4*)xb16)[i] = o;
    return;
  }
  id -= 512;
  {                                                // zero WxT pad rows 2080..2175
    unsigned short* p = WxT + (size_t)(2080 + id) * 2048 + tid * 8;
    ushort4 z = {0,0,0,0};
    *(ushort4*)p = z; *(ushort4*)(p + 4) = z;
  }
}

// ---------- gemm2ph: 128x128 tile, BK=64, 8 waves, 2-phase schedule ----------
// stage(next) before compute, vmcnt(0)+barrier per tile (r15-proven).
// MODE: 1 softplus(v+bias) f32; 3 split xz; 4 proj split
template<int MODE>
__global__ __launch_bounds__(512)
void gemm2ph(const unsigned short* __restrict__ A, const unsigned short* __restrict__ B,
             int M, int N, int K, int lda, int ldb,
             const float* __restrict__ bias,
             void* __restrict__ out0, void* __restrict__ out1)
{
  __shared__ __align__(1024) unsigned short S[2][256*64];   // 64 KB
  const int tid = threadIdx.x;
  const int lane = tid & 63, w = tid >> 6;
  const int row0 = blockIdx.y * 128, col0 = blockIdx.x * 128;
  const int wr = (w >> 2) * 64, wc = (w & 3) * 32;
  const int l15 = lane & 15, lg4 = lane >> 4;

  int afo[4][2], bfo[2][2];
  #pragma unroll
  for (int fi = 0; fi < 4; ++fi)
    #pragma unroll
    for (int h = 0; h < 2; ++h) {
      const int r = wr + fi*16 + l15;
      const int q = h*4 + lg4;
      afo[fi][h] = r*64 + (q ^ (r & 7))*8;
    }
  #pragma unroll
  for (int fj = 0; fj < 2; ++fj)
    #pragma unroll
    for (int h = 0; h < 2; ++h) {
      const int r = wc + fj*16 + l15;
      const int q = h*4 + lg4;
      bfo[fj][h] = (128 + r)*64 + (q ^ (r & 7))*8;
    }

  const unsigned short* src[4];
  int dsto[4];
  #pragma unroll
  for (int i = 0; i < 4; ++i) {
    const int base = w*32 + i*8;
    const int row = base + (lane >> 3);
    const int gs = (lane & 7) ^ (row & 7);
    dsto[i] = base*64;
    src[i] = (row < 128) ? A + (size_t)(row0 + row) * lda + gs*8
                         : B + (size_t)(col0 + row - 128) * ldb + gs*8;
  }

  f32x4 acc[4][2];
  #pragma unroll
  for (int i=0;i<4;i++)
    #pragma unroll
    for (int j=0;j<2;j++) acc[i][j] = (f32x4){0.f,0.f,0.f,0.f};

  const int NT = K >> 6;

  auto stage = [&](int buf) {
    #pragma unroll
    for (int i = 0; i < 4; ++i) { gload16(src[i], &S[buf][dsto[i]]); src[i] += 64; }
  };

  stage(0);
  asm volatile("s_waitcnt vmcnt(0)" ::: "memory");
  __builtin_amdgcn_s_barrier();
  asm volatile("" ::: "memory");

  int cur = 0;
  for (int t = 0; t < NT; ++t) {
    if (t + 1 < NT) stage(cur ^ 1);
    #pragma unroll
    for (int h = 0; h < 2; ++h) {
      bf16x8 af[4], bfv[2];
      #pragma unroll
      for (int fi = 0; fi < 4; ++fi) af[fi] = *(const bf16x8*)&S[cur][afo[fi][h]];
      #pragma unroll
      for (int fj = 0; fj < 2; ++fj) bfv[fj] = *(const bf16x8*)&S[cur][bfo[fj][h]];
      __builtin_amdgcn_s_setprio(1);
      #pragma unroll
      for (int fi = 0; fi < 4; ++fi)
        #pragma unroll
        for (int fj = 0; fj < 2; ++fj)
          acc[fi][fj] = __builtin_amdgcn_mfma_f32_16x16x32_bf16(af[fi], bfv[fj], acc[fi][fj], 0, 0, 0);
      __builtin_amdgcn_s_setprio(0);
    }
    asm volatile("s_waitcnt vmcnt(0) lgkmcnt(0)" ::: "memory");
    __builtin_amdgcn_s_barrier();
    asm volatile("" ::: "memory");
    cur ^= 1;
  }

  #pragma unroll
  for (int fi=0; fi<4; fi++){
    const int rb = row0 + wr + fi*16 + lg4*4;
    #pragma unroll
    for (int fj=0; fj<2; fj++){
      const int c = col0 + wc + fj*16 + l15;
      #pragma unroll
      for (int q=0;q<4;q++){
        const int r = rb + q;
        float v = acc[fi][fj][q];
        if constexpr (MODE == 1) {
          if (c < N) { v += bias[c]; v = (v > 20.f) ? v : log1pf(__expf(v));
                       ((float*)out0)[(size_t)r*N + c] = v; }
        } else if constexpr (MODE == 3) {
          if (c < 2048) ((float*)out0)[(size_t)r*2048 + c] = v;
          else          ((unsigned short*)out1)[(size_t)r*2048 + (c - 2048)] = f2bf(v);
        } else {
          if (c < 32) ((float*)out0)[(size_t)r*32 + c] = v;
          else if (c < N) ((unsigned short*)out1)[(size_t)r*2048 + (c - 32)] = f2bf(v);
        }
      }
    }
  }
}

// ------------- bf16 MFMA GEMM, reg-staged, depth-4 register pipeline ---------
// MODE: 0 f32 out (+bias); 2 bf16 out; 5 split-K fp32 partials.
template<int BM, int BN, int MODE>
__global__ __launch_bounds__(256)
void gemm_bf16(const unsigned short* __restrict__ A, const unsigned short* __restrict__ B,
               int M, int N, int K, int lda, int ldb,
               const float* __restrict__ bias,
               void* __restrict__ out0, void* __restrict__ out1)
{
  constexpr int FM = BM / 32;
  constexpr int FN = BN / 32;
  constexpr int ROWS = BM + BN;
  constexpr int GR = ROWS / 64;
  __shared__ __align__(1024) unsigned short S[2][ROWS*32];

  const int tid = threadIdx.x;
  const int lane = tid & 63, w = tid >> 6;
  const int row0 = blockIdx.y * BM, col0 = blockIdx.x * BN;
  const int wr = (w >> 1) * (BM/2), wc = (w & 1) * (BN/2);
  const int l15 = lane & 15, lg4 = lane >> 4;

  size_t zoff = 0;
  if constexpr (MODE == 5) {
    A += (size_t)blockIdx.z * (size_t)K;
    B += (size_t)blockIdx.z * (size_t)K;
    zoff = (size_t)blockIdx.z * (size_t)(gridDim.y * BM) * (size_t)N;
  }

  int afo[FM], bfo[FN];
  #pragma unroll
  for (int fi = 0; fi < FM; ++fi) {
    const int r = wr + fi*16 + l15;
    afo[fi] = r*32 + (lg4 ^ ((r >> 1) & 3))*8;
  }
  #pragma unroll
  for (int fj = 0; fj < FN; ++fj) {
    const int r = wc + fj*16 + l15;
    bfo[fj] = (BM + r)*32 + (lg4 ^ ((r >> 1) & 3))*8;
  }

  const unsigned short* src[GR];
  int ldso[GR];
  #pragma unroll
  for (int i = 0; i < GR; ++i) {
    const int g = tid + i*256;
    const int row = g >> 2, q = g & 3;
    ldso[i] = row*32 + (q ^ ((row >> 1) & 3))*8;
    src[i] = (row < BM) ? A + (size_t)(row0 + row) * lda + q*8
                        : B + (size_t)(col0 + row - BM) * ldb + q*8;
  }

  f32x4 acc[FM][FN];
  #pragma unroll
  for (int i=0;i<FM;i++)
    #pragma unroll
    for (int j=0;j<FN;j++) acc[i][j] = (f32x4){0.f,0.f,0.f,0.f};

  const int NT = K >> 5;
  bf16x8 g0[GR], g1[GR], g2[GR], g3[GR];

  auto loadg = [&](bf16x8 (&g)[GR]) {
    #pragma unroll
    for (int i = 0; i < GR; ++i) { g[i] = *(const bf16x8*)src[i]; src[i] += 32; }
  };

  loadg(g0); loadg(g1); loadg(g2); loadg(g3);
  #pragma unroll
  for (int i = 0; i < GR; ++i) *(bf16x8*)(&S[0][ldso[i]]) = g0[i];
  asm volatile("s_waitcnt lgkmcnt(0)" ::: "memory");
  __builtin_amdgcn_s_barrier();
  asm volatile("" ::: "memory");

#define STEP(I) do {                                                          \
    const int j = base + (I);                                                 \
    if (j < NT) {                                                             \
      bf16x8 af[FM], bfv[FN];                                                 \
      _Pragma("unroll")                                                       \
      for (int fi = 0; fi < FM; ++fi)                                         \
        af[fi] = *(const bf16x8*)&S[(I)&1][afo[fi]];                          \
      _Pragma("unroll")                                                       \
      for (int fj = 0; fj < FN; ++fj)                                         \
        bfv[fj] = *(const bf16x8*)&S[(I)&1][bfo[fj]];                         \
      if (j + 4 < NT) loadg(pick4<(I)&3>(g0, g1, g2, g3));                    \
      _Pragma("unroll")                                                       \
      for (int fi = 0; fi < FM; ++fi)                                         \
        _Pragma("unroll")                                                     \
        for (int fj = 0; fj < FN; ++fj)                                       \
          acc[fi][fj] = __builtin_amdgcn_mfma_f32_16x16x32_bf16(              \
              af[fi], bfv[fj], acc[fi][fj], 0, 0, 0);                         \
      if (j + 1 < NT) {                                                       \
        bf16x8 (&gw)[GR] = pick4<((I)+1)&3>(g0, g1, g2, g3);                  \
        _Pragma("unroll")                                                     \
        for (int i = 0; i < GR; ++i)                                          \
          *(bf16x8*)(&S[((I)+1)&1][ldso[i]]) = gw[i];                         \
      }                                                                       \
      asm volatile("s_waitcnt lgkmcnt(0)" ::: "memory");                      \
      __builtin_amdgcn_s_barrier();                                           \
      asm volatile("" ::: "memory");                                          \
    }                                                                         \
  } while (0)

  for (int base = 0; base < NT; base += 4) {
    STEP(0); STEP(1); STEP(2); STEP(3);
  }
#undef STEP

  #pragma unroll
  for (int fi=0; fi<FM; fi++){
    const int rb = row0 + wr + fi*16 + lg4*4;
    #pragma unroll
    for (int fj=0; fj<FN; fj++){
      const int c = col0 + wc + fj*16 + l15;
      #pragma unroll
      for (int q=0;q<4;q++){
        const int r = rb + q;
        float v = acc[fi][fj][q];
        if constexpr (MODE == 0) {
          if (c < N) ((float*)out0)[(size_t)r*N + c] = bias ? v + bias[c] : v;
        } else if constexpr (MODE == 2) {
          if (c < N) ((unsigned short*)out0)[(size_t)r*N + c] = f2bf(v);
        } else {
          if (c < N) ((float*)out0)[zoff + (size_t)r*N + c] = v;
        }
      }
    }
  }
}

// reduce 4 fp32 partials [256*2048] -> bf16
__global__ __launch_bounds__(256)
void red4_wf(const float* __restrict__ p, unsigned short* __restrict__ out)
{
  const size_t S = (size_t)256*2048;
  const int i = (blockIdx.x * 256 + threadIdx.x) * 4;
  float4 a = *(const float4*)(p + i);
  float4 b = *(const float4*)(p + S + i);
  float4 c = *(const float4*)(p + 2*S + i);
  float4 d = *(const float4*)(p + 3*S + i);
  ushort4 o;
  o.x = f2bf(a.x+b.x+c.x+d.x);
  o.y = f2bf(a.y+b.y+c.y+d.y);
  o.z = f2bf(a.z+b.z+c.z+d.z);
  o.w = f2bf(a.w+b.w+c.w+d.w);
  *(ushort4*)(out + i) = o;
}

// reduce 4 fp32 partials [2048*256] + bias[col] -> fp32 out
__global__ __launch_bounds__(256)
void red4_out(const float* __restrict__ p, const float* __restrict__ bias,
              float* __restrict__ out)
{
  const size_t S = (size_t)2048*256;
  const int i = (blockIdx.x * 256 + threadIdx.x) * 4;
  float4 a = *(const float4*)(p + i);
  float4 b = *(const float4*)(p + S + i);
  float4 c = *(const float4*)(p + 2*S + i);
  float4 d = *(const float4*)(p + 3*S + i);
  float4 bb = *(const float4*)(bias + (i & 255));
  float4 o;
  o.x = a.x+b.x+c.x+d.x + bb.x;
  o.y = a.y+b.y+c.y+d.y + bb.y;
  o.z = a.z+b.z+c.z+d.z + bb.z;
  o.w = a.w+b.w+c.w+d.w + bb.w;
  *(float4*)(out + i) = o;
}

// LayerNorm: read fp32 h, write bf16
__global__ __launch_bounds__(256)
void ln_k(const float* __restrict__ h, const float* __restrict__ gamma,
          const float* __restrict__ beta, unsigned short* __restrict__ hb)
{
  const int row = blockIdx.x;
  const float* p = h + (size_t)row * D_MODEL;
  float s = 0.f, s2 = 0.f;
  for (int i = threadIdx.x; i < D_MODEL; i += 256) { float v = p[i]; s += v; s2 += v*v; }
  #pragma unroll
  for (int off = 32; off; off >>= 1) { s += __shfl_down(s, off, 64); s2 += __shfl_down(s2, off, 64); }
  __shared__ float ss[4], ss2[4];
  __shared__ float smu, sinv;
  const int wid = threadIdx.x >> 6;
  if ((threadIdx.x & 63) == 0) { ss[wid] = s; ss2[wid] = s2; }
  __syncthreads();
  if (threadIdx.x == 0) {
    float S = ss[0]+ss[1]+ss[2]+ss[3];
    float S2 = ss2[0]+ss2[1]+ss2[2]+ss2[3];
    float mu = S * (1.f / D_MODEL);
    float var = S2 * (1.f / D_MODEL) - mu * mu;
    smu = mu; sinv = rsqrtf(var + 1e-5f);
  }
  __syncthreads();
  const float mu = smu, inv = sinv;
  unsigned short* q = hb + (size_t)row * D_MODEL;
  for (int i = threadIdx.x; i < D_MODEL; i += 256)
    q[i] = f2bf((p[i] - mu) * inv * gamma[i] + beta[i]);
}

// conv+silu, float4 over d: read xb fp32 [NTOK][2048], write u bf16
__global__ __launch_bounds__(256)
void conv_silu_k(const float* __restrict__ xb, const float* __restrict__ cw,
                 const float* __restrict__ cb, unsigned short* __restrict__ ub)
{
  const int idx = blockIdx.x * 256 + threadIdx.x;   // group of 4 d's
  const int d4 = (idx & 511) * 4;
  const int bt = idx >> 9;
  const int t  = bt & (SEQ - 1);
  float4 acc = *(const float4*)(cb + d4);
  const float* base = xb + (size_t)bt * D_INNER + d4;
  #pragma unroll
  for (int k = 0; k < D_CONV; ++k) {
    int tt = t + k - (D_CONV - 1);
    if (tt >= 0) {
      float4 xv = *(const float4*)(base + (ptrdiff_t)(k - (D_CONV-1)) * D_INNER);
      acc.x = fmaf(cw[(d4+0)*D_CONV + k], xv.x, acc.x);
      acc.y = fmaf(cw[(d4+1)*D_CONV + k], xv.y, acc.y);
      acc.z = fmaf(cw[(d4+2)*D_CONV + k], xv.z, acc.z);
      acc.w = fmaf(cw[(d4+3)*D_CONV + k], xv.w, acc.w);
    }
  }
  ushort4 o;
  o.x = f2bf(siluf(acc.x)); o.y = f2bf(siluf(acc.y));
  o.z = f2bf(siluf(acc.z)); o.w = f2bf(siluf(acc.w));
  *(ushort4*)(ub + (size_t)bt * D_INNER + d4) = o;
}

// ---- chunk-parallel scan, CHUNK=16, compact 17-slot summaries ----
// summ layout: [b][c][17][D_INNER]; slot 0 = dtsum, slots 1..16 = hl (p1)
// -> hierarchical stitch (p2a/p2b/p2c) overwrites slots 1..16 with chunk-START
// state; p3 reads them. gsum: [b][g][17][D_INNER] group summaries / starts.
__global__ __launch_bounds__(256)
void scan_p1(const float* __restrict__ dtb, const unsigned short* __restrict__ ub,
             const float* __restrict__ BC, const float* __restrict__ A_log,
             float* __restrict__ summ)
{
  const int bid = blockIdx.x;                 // b*512 + c*8 + blk
  const int b = bid >> 9;
  const int c = (bid >> 3) & (NCHUNK - 1);
  const int d = ((bid & 7) << 8) + threadIdx.x;
  float A[D_STATE], hl[D_STATE];
  #pragma unroll
  for (int n = 0; n < D_STATE; ++n) { A[n] = -__expf(A_log[d*D_STATE + n]); hl[n] = 0.f; }
  float dtsum = 0.f;
  const size_t row0 = (size_t)b * SEQ + (size_t)c * CHUNK;
  float dtv = dtb[row0*D_INNER + d];
  float uv  = bf2f(ub[row0*D_INNER + d]);
  float Bv[D_STATE];
  #pragma unroll
  for (int n = 0; n < D_STATE; ++n) Bv[n] = BC[row0*32 + n];
  for (int t = 0; t < CHUNK; ++t) {
    const size_t rn = row0 + ((t+1 < CHUNK) ? (t+1) : t);
    float ndt = dtb[rn*D_INNER + d];
    float nu  = bf2f(ub[rn*D_INNER + d]);
    float nB[D_STATE];
    #pragma unroll
    for (int n = 0; n < D_STATE; ++n) nB[n] = BC[rn*32 + n];
    const float du = dtv * uv;
    dtsum += dtv;
    #pragma unroll
    for (int n = 0; n < D_STATE; ++n) {
      float dA = __expf(dtv * A[n]);
      hl[n] = fmaf(dA, hl[n], du * Bv[n]);
    }
    dtv = ndt; uv = nu;
    #pragma unroll
    for (int n = 0; n < D_STATE; ++n) Bv[n] = nB[n];
  }
  float* s = summ + (((size_t)b*NCHUNK + c)*17)*D_INNER + d;
  s[0] = dtsum;
  #pragma unroll
  for (int n = 0; n < D_STATE; ++n)
    s[(size_t)(1+n)*D_INNER] = hl[n];
}

// p2a: fold 8 chunk summaries into a group summary (128 blocks, 8 serial iters)
__global__ __launch_bounds__(256)
void scan_p2a(const float* __restrict__ summ, const float* __restrict__ A_log,
              float* __restrict__ gsum)
{
  const int bid = blockIdx.x;                 // b*64 + g*8 + dblk
  const int b = bid >> 6;
  const int g = (bid >> 3) & (GROUPS - 1);
  const int d = ((bid & 7) << 8) + threadIdx.x;
  float A[D_STATE], Lg[D_STATE];
  #pragma unroll
  for (int n = 0; n < D_STATE; ++n) { A[n] = -__expf(A_log[d*D_STATE + n]); Lg[n] = 0.f; }
  float dtsg = 0.f;
  for (int j = 0; j < GCH; ++j) {
    const int c = g*GCH + j;
    const float* s = summ + (((size_t)b*NCHUNK + c)*17)*D_INNER + d;
    const float dts = s[0];
    #pragma unroll
    for (int n = 0; n < D_STATE; ++n) {
      float p = __expf(A[n] * dts);
      Lg[n] = fmaf(p, Lg[n], s[(size_t)(1+n)*D_INNER]);
    }
    dtsg += dts;
  }
  float* gs = gsum + (((size_t)b*GROUPS + g)*17)*D_INNER + d;
  gs[0] = dtsg;
  #pragma unroll
  for (int n = 0; n < D_STATE; ++n)
    gs[(size_t)(1+n)*D_INNER] = Lg[n];
}

// p2b: stitch 8 groups; write group-START states into gsum; emit hT (16 blocks)
__global__ __launch_bounds__(256)
void scan_p2b(float* __restrict__ gsum, const float* __restrict__ h0,
              const float* __restrict__ A_log, float* __restrict__ outH)
{
  const int b = blockIdx.x >> 3;
  const int d = ((blockIdx.x & 7) << 8) + threadIdx.x;
  float A[D_STATE], h[D_STATE];
  #pragma unroll
  for (int n = 0; n < D_STATE; ++n) {
    A[n] = -__expf(A_log[d*D_STATE + n]);
    h[n] = h0[((size_t)b*D_INNER + d)*D_STATE + n];
  }
  for (int g = 0; g < GROUPS; ++g) {
    float* gs = gsum + (((size_t)b*GROUPS + g)*17)*D_INNER + d;
    const float dts = gs[0];
    #pragma unroll
    for (int n = 0; n < D_STATE; ++n) {
      float L = gs[(size_t)(1+n)*D_INNER];
      gs[(size_t)(1+n)*D_INNER] = h[n];        // group-start state
      h[n] = fmaf(__expf(A[n] * dts), h[n], L);
    }
  }
  #pragma unroll
  for (int n = 0; n < D_STATE; ++n)
    outH[((size_t)b*D_INNER + d)*D_STATE + n] = h[n];
}

// p2c: walk chunks within each group from group-start; write chunk-START states
__global__ __launch_bounds__(256)
void scan_p2c(float* __restrict__ summ, const float* __restrict__ gsum,
              const float* __restrict__ A_log)
{
  const int bid = blockIdx.x;                 // b*64 + g*8 + dblk
  const int b = bid >> 6;
  const int g = (bid >> 3) & (GROUPS - 1);
  const int d = ((bid & 7) << 8) + threadIdx.x;
  float A[D_STATE], h[D_STATE];
  const float* gs = gsum + (((size_t)b*GROUPS + g)*17)*D_INNER + d;
  #pragma unroll
  for (int n = 0; n < D_STATE; ++n) {
    A[n] = -__expf(A_log[d*D_STATE + n]);
    h[n] = gs[(size_t)(1+n)*D_INNER];
  }
  for (int j = 0; j < GCH; ++j) {
    const int c = g*GCH + j;
    float* s = summ + (((size_t)b*NCHUNK + c)*17)*D_INNER + d;
    const float dts = s[0];
    #pragma unroll
    for (int n = 0; n < D_STATE; ++n) {
      float hl = s[(size_t)(1+n)*D_INNER];
      s[(size_t)(1+n)*D_INNER] = h[n];         // chunk-start state
      h[n] = fmaf(__expf(A[n] * dts), h[n], hl);
    }
  }
}

__global__ __launch_bounds__(256)
void scan_p3(const float* __restrict__ dtb, const unsigned short* __restrict__ ub,
             const unsigned short* __restrict__ zbh, const float* __restrict__ BC,
             const float* __restrict__ A_log, const float* __restrict__ D_skip,
             const float* __restrict__ summ, unsigned short* __restrict__ yb)
{
  const int bid = blockIdx.x;
  const int b = bid >> 9;
  const int c = (bid >> 3) & (NCHUNK - 1);
  const int d = ((bid & 7) << 8) + threadIdx.x;
  float A[D_STATE], h[D_STATE];
  const float* s = summ + (((size_t)b*NCHUNK + c)*17)*D_INNER + d;
  #pragma unroll
  for (int n = 0; n < D_STATE; ++n) {
    A[n] = -__expf(A_log[d*D_STATE + n]);
    h[n] = s[(size_t)(1+n)*D_INNER];
  }
  const float Ds = D_skip[d];
  const size_t row0 = (size_t)b * SEQ + (size_t)c * CHUNK;
  float dtv = dtb[row0*D_INNER + d];
  float uv  = bf2f(ub[row0*D_INNER + d]);
  float zv  = bf2f(zbh[row0*D_INNER + d]);
  float Bv[D_STATE], Cv[D_STATE];
  #pragma unroll
  for (int n = 0; n < D_STATE; ++n) { Bv[n] = BC[row0*32 + n]; Cv[n] = BC[row0*32 + 16 + n]; }
  for (int t = 0; t < CHUNK; ++t) {
    const size_t r = row0 + t;
    const size_t rn = row0 + ((t+1 < CHUNK) ? (t+1) : t);
    float ndt = dtb[rn*D_INNER + d];
    float nu  = bf2f(ub[rn*D_INNER + d]);
    float nz  = bf2f(zbh[rn*D_INNER + d]);
    float nB[D_STATE], nC[D_STATE];
    #pragma unroll
    for (int n = 0; n < D_STATE; ++n) { nB[n] = BC[rn*32 + n]; nC[n] = BC[rn*32 + 16 + n]; }
    const float du = dtv * uv;
    float y = 0.f;
    #pragma unroll
    for (int n = 0; n < D_STATE; ++n) {
      float dA = __expf(dtv * A[n]);
      h[n] = fmaf(dA, h[n], du * Bv[n]);
      y = fmaf(h[n], Cv[n], y);
    }
    y = fmaf(uv, Ds, y);
    yb[r*D_INNER + d] = f2bf(y * siluf(zv));
    dtv = ndt; uv = nu; zv = nz;
    #pragma unroll
    for (int n = 0; n < D_STATE; ++n) { Bv[n] = nB[n]; Cv[n] = nC[n]; }
  }
}

extern "C" void kernel_launch(void* const* d_in, const int* in_sizes, int n_in,
                              void* d_out, int out_size, void* d_ws, size_t ws_size,
                              hipStream_t stream) {
  const float* x          = (const float*)d_in[0];
  const float* h0         = (const float*)d_in[1];
  const float* W_in_wrap  = (const float*)d_in[2];
  const float* b_in_wrap  = (const float*)d_in[3];
  const float* ln_g       = (const float*)d_in[4];
  const float* ln_b       = (const float*)d_in[5];
  const float* W_in       = (const float*)d_in[6];
  const float* conv_w     = (const float*)d_in[7];
  const float* conv_b     = (const float*)d_in[8];
  const float* W_x        = (const float*)d_in[9];
  const float* W_dt       = (const float*)d_in[10];
  const float* b_dt       = (const float*)d_in[11];
  const float* A_log      = (const float*)d_in[12];
  const float* D_skip     = (const float*)d_in[13];
  const float* W_out      = (const float*)d_in[14];
  const float* W_out_wrap = (const float*)d_in[15];
  const float* b_out_wrap = (const float*)d_in[16];

  float* out  = (float*)d_out;                       // (B,T,OUT_DIM)
  float* outH = out + (size_t)NTOK * OUT_DIM;        // (B,D_INNER,D_STATE)

  char* ws = (char*)d_ws;
  auto at = [&](size_t kb){ return (void*)(ws + kb*1024); };
  float*          hbuf = (float*)at(0);        // 8 MB: Wf partials -> h fp32 -> gsum
  float*          wfp  = hbuf;
  float*          gsum = hbuf;                 // 2.23 MB group summaries (after ln_k)
  float*          xb   = (float*)at(8192);     // 16 MB fp32 x_branch (then dtb, then out partials)
  float*          dtb  = xb;
  float*          outp = xb;
  unsigned short* zbh  = (unsigned short*)at(24576);  // 8 MB bf16 z
  unsigned short* WfT  = (unsigned short*)at(32768);  // 1 MB bf16 W_fused^T [256][2048]
  unsigned short* ub   = (unsigned short*)at(40960);  // 8 MB bf16 u (xb16 early)
  unsigned short* xb16 = ub;
  unsigned short* gb   = (unsigned short*)at(49152);  // 8 MB bf16 gate (WiwT early; yb later)
  unsigned short* WiwT = gb;
  unsigned short* yb   = gb;
  unsigned short* hb   = (unsigned short*)at(57344);  // 4 MB bf16 h_ln
  float*          BC   = (float*)at(61440);    // 256 KB fp32 [NTOK][32]
  unsigned short* WinT = (unsigned short*)at(61696);  // 8 MB (dead after xz)
  unsigned short* WxT  = (unsigned short*)at(69888);  // 8.5 MB (dead after proj)
  float*          summ = (float*)at(61696);    // 17 MB compact summaries (over dead WinT/WxT/+0.5MB of WdtT)
  unsigned short* WdtT = (unsigned short*)at(78592);  // 8 MB (dead after dt GEMM)
  unsigned short* Wob  = (unsigned short*)at(86784);  // 4 MB W_out bf16 [2048][1024]
  unsigned short* WwrT = (unsigned short*)at(90880);  // 512 KB [256][1024] (ends 89.25 MB)

  dim3 blk(256);
  dim3 blk512(512);
  // 0) fused prep (1 launch)
  prep_k<<<dim3(15520), blk, 0, stream>>>(x, W_in_wrap, W_in, W_x, W_dt, W_out, W_out_wrap,
                                          xb16, WiwT, WinT, WxT, WdtT, Wob, WwrT);
  // 0b) Wf partials = WwrT @ Wob, split-K x4 (512 blocks, NT=8)
  gemm_bf16<64,64,5><<<dim3(2048/64, 256/64, 4), blk, 0, stream>>>(WwrT, Wob, 256, 2048, 1024/4,
                                                                   1024, 1024, nullptr, wfp, nullptr);
  // 0c) WfT = sum partials -> bf16
  red4_wf<<<dim3(512), blk, 0, stream>>>(wfp, WfT);
  // 1) h = x @ W_in_wrap + b_in_wrap  (512 blocks, NT=8)
  gemm_bf16<64,64,0><<<dim3(1024/64, NTOK/64), blk, 0, stream>>>(xb16, WiwT, NTOK, 1024, 256,
                                                                 256, 256, b_in_wrap, hbuf, nullptr);
  // 2) LayerNorm -> bf16 (hbuf free afterwards -> gsum)
  ln_k<<<dim3(NTOK), blk, 0, stream>>>(hbuf, ln_g, ln_b, hb);
  // 3) xz = h @ W_in -> xb fp32 | z bf16   (2-phase, 512 blocks)
  gemm2ph<3><<<dim3(4096/128, NTOK/128), blk512, 0, stream>>>(hb, WinT, NTOK, 4096, 1024,
                                                              1024, 1024, nullptr, xb, zbh);
  // 4) u = silu(conv(xb)) -> bf16 (float4, 4096 blocks)
  conv_silu_k<<<dim3(NTOK*D_INNER/4/256), blk, 0, stream>>>(xb, conv_w, conv_b, ub);
  // 5) proj = u @ W_x -> BC fp32 | g bf16  (2-phase, 272 blocks)
  gemm2ph<4><<<dim3(2176/128, NTOK/128), blk512, 0, stream>>>(ub, WxT, NTOK, PROJ_N, 2048,
                                                              2048, 2048, nullptr, BC, gb);
  // 6) dt = softplus(g @ W_dt + b_dt) -> fp32 (2-phase, 256 blocks)
  gemm2ph<1><<<dim3(2048/128, NTOK/128), blk512, 0, stream>>>(gb, WdtT, NTOK, 2048, 2048,
                                                              2048, 2048, b_dt, dtb, nullptr);
  // 7) chunk-parallel scan, hierarchical stitch (8/8/8 instead of 64 serial)
  scan_p1<<<dim3(BATCH*NCHUNK*(D_INNER/256)), blk, 0, stream>>>(dtb, ub, BC, A_log, summ);
  scan_p2a<<<dim3(BATCH*GROUPS*(D_INNER/256)), blk, 0, stream>>>(summ, A_log, gsum);
  scan_p2b<<<dim3(BATCH*(D_INNER/256)), blk, 0, stream>>>(gsum, h0, A_log, outH);
  scan_p2c<<<dim3(BATCH*GROUPS*(D_INNER/256)), blk, 0, stream>>>(summ, gsum, A_log);
  scan_p3<<<dim3(BATCH*NCHUNK*(D_INNER/256)), blk, 0, stream>>>(dtb, ub, zbh, BC, A_log, D_skip, summ, yb);
  // 8) out partials = y @ W_fused, split-K x4 (512 blocks, NT=16)
  gemm_bf16<64,64,5><<<dim3(256/64, NTOK/64, 4), blk, 0, stream>>>(yb, WfT, NTOK, 256, 2048/4,
                                                                   2048, 2048, nullptr, outp, nullptr);
  // 8b) out = sum partials + b_out_wrap (fp32)
  red4_out<<<dim3(512), blk, 0, stream>>>(outp, b_out_wrap, out);
}